// Round 1
// baseline (836.165 us; speedup 1.0000x reference)
//
#include <hip/hip_runtime.h>
#include <hip/hip_bf16.h>
#include <stdint.h>

#define B_    2
#define N_    2048
#define DIM_  2048
#define H_    16
#define HD_   128
#define NH3   6144            // 3*H*HD
#define ROWS  4096            // B*N
#define EPS_  1e-5f

typedef unsigned short u16;
typedef __bf16 bf16x8 __attribute__((ext_vector_type(8)));
typedef float  f32x4  __attribute__((ext_vector_type(4)));

__device__ inline f32x4 mfma16(bf16x8 a, bf16x8 b, f32x4 c) {
  return __builtin_amdgcn_mfma_f32_16x16x32_bf16(a, b, c, 0, 0, 0);
}

__device__ inline u16 f2bf(float f) {
  union { float f; uint32_t u; } v; v.f = f;
  uint32_t u = v.u;
  return (u16)((u + 0x7fffu + ((u >> 16) & 1u)) >> 16);   // RNE
}
__device__ inline float bf2f(u16 u) {
  union { uint32_t u; float f; } v; v.u = ((uint32_t)u) << 16;
  return v.f;
}

// ---------------- elementwise f32 -> bf16 ----------------
__global__ __launch_bounds__(256) void cvt_f32_bf16(const float* __restrict__ in,
                                                    u16* __restrict__ out, int n) {
  int i = (blockIdx.x * 256 + threadIdx.x) * 4;
  if (i >= n) return;
  float4 v = *(const float4*)&in[i];
  ushort4 o;
  o.x = f2bf(v.x); o.y = f2bf(v.y); o.z = f2bf(v.z); o.w = f2bf(v.w);
  *(ushort4*)&out[i] = o;
}

// ---------------- tiled transpose + convert: in RxC f32 -> out CxR bf16 ----------------
__global__ __launch_bounds__(256) void transpose_cvt(const float* __restrict__ in,
                                                     u16* __restrict__ out,
                                                     int R, int C) {
  __shared__ float tile[32][33];
  int tc = blockIdx.x * 32, tr = blockIdx.y * 32;
  int tx = threadIdx.x, ty = threadIdx.y;          // 32 x 8
  #pragma unroll
  for (int i = 0; i < 4; ++i)
    tile[ty + i*8][tx] = in[(size_t)(tr + ty + i*8) * C + tc + tx];
  __syncthreads();
  #pragma unroll
  for (int i = 0; i < 4; ++i)
    out[(size_t)(tc + ty + i*8) * R + tr + tx] = f2bf(tile[tx][ty + i*8]);
}

// ---------------- bf16 GEMM: A (MxK row-major) * Bt^T (Bt is NxK row-major) ----------------
// 128x128 tile, BK=64, 4 waves (2x2), each wave 64x64 via 4x4 16x16x32 MFMAs.
template <bool OUT_BF16>
__global__ __launch_bounds__(256) void gemm_bt(const u16* __restrict__ A,
                                               const u16* __restrict__ Bt,
                                               void* __restrict__ Cv,
                                               int M, int N, int K) {
  __shared__ u16 lA[128][72];   // pad 8 bf16: 2-way bank aliasing only
  __shared__ u16 lB[128][72];
  int m0 = blockIdx.x * 128, n0 = blockIdx.y * 128;
  int t = threadIdx.x;
  int wave = t >> 6, lane = t & 63;
  int wr = wave >> 1, wc = wave & 1;
  int lhi = lane >> 4, llo = lane & 15;
  f32x4 acc[4][4] = {};

  for (int k0 = 0; k0 < K; k0 += 64) {
    __syncthreads();
    #pragma unroll
    for (int i = 0; i < 4; ++i) {
      int chunk = i * 256 + t;          // 1024 chunks of 8 bf16
      int row = chunk >> 3, kc = chunk & 7;
      *(int4*)&lA[row][kc*8] = *(const int4*)&A[(size_t)(m0+row)*K + k0 + kc*8];
      *(int4*)&lB[row][kc*8] = *(const int4*)&Bt[(size_t)(n0+row)*K + k0 + kc*8];
    }
    __syncthreads();
    #pragma unroll
    for (int kk = 0; kk < 2; ++kk) {
      bf16x8 af[4], bfr[4];
      #pragma unroll
      for (int mi = 0; mi < 4; ++mi)
        af[mi] = *(const bf16x8*)&lA[wr*64 + mi*16 + llo][kk*32 + lhi*8];
      #pragma unroll
      for (int ni = 0; ni < 4; ++ni)
        bfr[ni] = *(const bf16x8*)&lB[wc*64 + ni*16 + llo][kk*32 + lhi*8];
      #pragma unroll
      for (int mi = 0; mi < 4; ++mi)
        #pragma unroll
        for (int ni = 0; ni < 4; ++ni)
          acc[mi][ni] = mfma16(af[mi], bfr[ni], acc[mi][ni]);
    }
  }
  #pragma unroll
  for (int mi = 0; mi < 4; ++mi)
    #pragma unroll
    for (int ni = 0; ni < 4; ++ni)
      #pragma unroll
      for (int r = 0; r < 4; ++r) {
        int row = m0 + wr*64 + mi*16 + lhi*4 + r;   // C/D: row=(lane>>4)*4+reg
        int col = n0 + wc*64 + ni*16 + llo;         //      col=lane&15
        float v = acc[mi][ni][r];
        if constexpr (OUT_BF16) ((u16*)Cv)[(size_t)row*N + col] = f2bf(v);
        else                    ((float*)Cv)[(size_t)row*N + col] = v;
      }
}

// ---------------- fused RMSNorm + RoPE on q,k (in-place on bf16 qkv) ----------------
// one wave per (row, head); lane handles pair (2*lane, 2*lane+1); folds 1/sqrt(HD) into q
__global__ __launch_bounds__(256) void norm_rope(u16* __restrict__ qkv,
                                                 const float* __restrict__ fr,
                                                 const float* __restrict__ fi,
                                                 const float* __restrict__ qw,
                                                 const float* __restrict__ kw) {
  int gw = (blockIdx.x * 256 + threadIdx.x) >> 6;
  int lane = threadIdx.x & 63;
  int row = gw >> 4, h = gw & 15;
  size_t base = (size_t)row * NH3 + h * HD_;
  ushort2 qp = *(ushort2*)&qkv[base + 2*lane];
  ushort2 kp = *(ushort2*)&qkv[base + 2048 + 2*lane];
  float q0 = bf2f(qp.x), q1 = bf2f(qp.y);
  float k0 = bf2f(kp.x), k1 = bf2f(kp.y);
  float sq = q0*q0 + q1*q1;
  float sk = k0*k0 + k1*k1;
  #pragma unroll
  for (int off = 1; off < 64; off <<= 1) {
    sq += __shfl_xor(sq, off);
    sk += __shfl_xor(sk, off);
  }
  float rq = rsqrtf(sq * (1.0f/128.0f) + EPS_);
  float rk = rsqrtf(sk * (1.0f/128.0f) + EPS_);
  float wq0 = qw[2*lane], wq1 = qw[2*lane+1];
  float wk0 = kw[2*lane], wk1 = kw[2*lane+1];
  q0 *= rq * wq0; q1 *= rq * wq1;
  k0 *= rk * wk0; k1 *= rk * wk1;
  float fre = fr[(size_t)row*64 + lane], fim = fi[(size_t)row*64 + lane];
  float qo0 = q0*fre - q1*fim, qo1 = q0*fim + q1*fre;
  float ko0 = k0*fre - k1*fim, ko1 = k0*fim + k1*fre;
  const float SC = 0.08838834764831845f;   // 1/sqrt(128), folded attention scale
  qo0 *= SC; qo1 *= SC;
  ushort2 qo, ko;
  qo.x = f2bf(qo0); qo.y = f2bf(qo1);
  ko.x = f2bf(ko0); ko.y = f2bf(ko1);
  *(ushort2*)&qkv[base + 2*lane] = qo;
  *(ushort2*)&qkv[base + 2048 + 2*lane] = ko;
}

// ---------------- flash attention: 64 q-rows/block (16/wave), KV tiles of 64 ----------------
__global__ __launch_bounds__(256) void attn(const u16* __restrict__ qkv,
                                            u16* __restrict__ out) {
  int bh = blockIdx.y;
  int b = bh >> 4, h = bh & 15;
  int q0 = blockIdx.x * 64;
  int t = threadIdx.x, wave = t >> 6, lane = t & 63;
  int lhi = lane >> 4, llo = lane & 15;

  __shared__ u16 lK[64][136];      // K tile row-major (+8 pad)
  __shared__ u16 lVt[128][72];     // V tile transposed: [d][kv] (+8 pad)
  __shared__ u16 lP[4][16][72];    // per-wave P tile (16 x 64, +8 pad)

  const u16* Qb = qkv + (size_t)b * N_ * NH3 + h * HD_;
  const u16* Kb = Qb + 2048;
  const u16* Vb = Qb + 4096;

  bf16x8 qf[4];
  {
    const u16* qrow = Qb + (size_t)(q0 + wave*16 + llo) * NH3;
    #pragma unroll
    for (int kk = 0; kk < 4; ++kk)
      qf[kk] = *(const bf16x8*)&qrow[kk*32 + lhi*8];
  }

  f32x4 o[8] = {};
  float m[4] = {-1e30f, -1e30f, -1e30f, -1e30f};
  float l[4] = {0.f, 0.f, 0.f, 0.f};

  for (int kv0 = 0; kv0 < N_; kv0 += 64) {
    __syncthreads();
    #pragma unroll
    for (int i = 0; i < 4; ++i) {                     // stage K (64x128)
      int chunk = i*256 + t;
      int row = chunk >> 4, kc = chunk & 15;
      *(int4*)&lK[row][kc*8] = *(const int4*)&Kb[(size_t)(kv0+row)*NH3 + kc*8];
    }
    #pragma unroll
    for (int i = 0; i < 4; ++i) {                     // stage V transposed (128x64)
      int chunk = i*256 + t;
      int row = chunk >> 4, dc = chunk & 15;
      int4 v = *(const int4*)&Vb[(size_t)(kv0+row)*NH3 + dc*8];
      u16* vs = (u16*)&v;
      #pragma unroll
      for (int e = 0; e < 8; ++e) lVt[dc*8+e][row] = vs[e];
    }
    __syncthreads();

    // S = Q K^T  (16 q-rows x 64 kv-cols per wave)
    f32x4 S[4];
    #pragma unroll
    for (int j = 0; j < 4; ++j) {
      f32x4 s = {0.f, 0.f, 0.f, 0.f};
      #pragma unroll
      for (int kk = 0; kk < 4; ++kk) {
        bf16x8 kf = *(const bf16x8*)&lK[j*16 + llo][kk*32 + lhi*8];
        s = mfma16(qf[kk], kf, s);
      }
      S[j] = s;
    }

    // online softmax (rows live at lane-group lhi, distributed over llo)
    float sc[4];
    #pragma unroll
    for (int r = 0; r < 4; ++r) {
      float rm = fmaxf(fmaxf(S[0][r], S[1][r]), fmaxf(S[2][r], S[3][r]));
      #pragma unroll
      for (int off = 1; off < 16; off <<= 1) rm = fmaxf(rm, __shfl_xor(rm, off));
      float mnew = fmaxf(m[r], rm);
      sc[r] = __expf(m[r] - mnew);
      m[r] = mnew;
    }
    #pragma unroll
    for (int r = 0; r < 4; ++r) {
      float s0 = __expf(S[0][r] - m[r]);
      float s1 = __expf(S[1][r] - m[r]);
      float s2 = __expf(S[2][r] - m[r]);
      float s3 = __expf(S[3][r] - m[r]);
      S[0][r] = s0; S[1][r] = s1; S[2][r] = s2; S[3][r] = s3;
      float rs = s0 + s1 + s2 + s3;
      #pragma unroll
      for (int off = 1; off < 16; off <<= 1) rs += __shfl_xor(rs, off);
      l[r] = l[r]*sc[r] + rs;
    }
    #pragma unroll
    for (int d = 0; d < 8; ++d)
      #pragma unroll
      for (int r = 0; r < 4; ++r) o[d][r] *= sc[r];

    // P -> LDS (C/D layout) -> A-fragment layout
    #pragma unroll
    for (int j = 0; j < 4; ++j)
      #pragma unroll
      for (int r = 0; r < 4; ++r)
        lP[wave][lhi*4 + r][j*16 + llo] = f2bf(S[j][r]);
    // same-wave LDS RAW: DS ops are in-order per wave; compiler inserts lgkmcnt

    #pragma unroll
    for (int kk = 0; kk < 2; ++kk) {
      bf16x8 pf = *(const bf16x8*)&lP[wave][llo][kk*32 + lhi*8];
      #pragma unroll
      for (int d = 0; d < 8; ++d) {
        bf16x8 vf = *(const bf16x8*)&lVt[d*16 + llo][kk*32 + lhi*8];
        o[d] = mfma16(pf, vf, o[d]);
      }
    }
  }

  #pragma unroll
  for (int r = 0; r < 4; ++r) l[r] = 1.0f / l[r];
  #pragma unroll
  for (int d = 0; d < 8; ++d)
    #pragma unroll
    for (int r = 0; r < 4; ++r) {
      size_t row = (size_t)b*N_ + q0 + wave*16 + lhi*4 + r;
      out[row*2048 + h*HD_ + d*16 + llo] = f2bf(o[d][r] * l[r]);
    }
}

extern "C" void kernel_launch(void* const* d_in, const int* in_sizes, int n_in,
                              void* d_out, int out_size, void* d_ws, size_t ws_size,
                              hipStream_t stream) {
  const float* x    = (const float*)d_in[0];
  const float* fr   = (const float*)d_in[1];
  const float* fi   = (const float*)d_in[2];
  const float* wqkv = (const float*)d_in[3];
  const float* wout = (const float*)d_in[4];
  const float* qw   = (const float*)d_in[5];
  const float* kw   = (const float*)d_in[6];
  float* out = (float*)d_out;

  char* ws = (char*)d_ws;
  const size_t SZ_XB    = (size_t)ROWS * DIM_ * 2;   // 16 MB
  const size_t SZ_WQKVT = (size_t)NH3  * DIM_ * 2;   // 24 MB
  const size_t SZ_WOUTT = (size_t)DIM_ * DIM_ * 2;   //  8 MB
  u16* xb    = (u16*)ws;
  u16* wqkvT = (u16*)(ws + SZ_XB);
  u16* woutT = (u16*)(ws + SZ_XB + SZ_WQKVT);
  u16* qkv   = (u16*)(ws + SZ_XB + SZ_WQKVT + SZ_WOUTT);
  u16* attno = xb;    // reuse: xb dead after GEMM1

  cvt_f32_bf16<<<(ROWS*DIM_/4 + 255)/256, 256, 0, stream>>>(x, xb, ROWS*DIM_);
  transpose_cvt<<<dim3(NH3/32, DIM_/32), dim3(32, 8), 0, stream>>>(wqkv, wqkvT, DIM_, NH3);
  transpose_cvt<<<dim3(DIM_/32, DIM_/32), dim3(32, 8), 0, stream>>>(wout, woutT, DIM_, DIM_);
  gemm_bt<true ><<<dim3(ROWS/128, NH3/128), 256, 0, stream>>>(xb, wqkvT, qkv, ROWS, NH3, DIM_);
  norm_rope<<<ROWS*H_/4, 256, 0, stream>>>(qkv, fr, fi, qw, kw);
  attn<<<dim3(N_/64, B_*H_), 256, 0, stream>>>(qkv, attno);
  gemm_bt<false><<<dim3(ROWS/128, DIM_/128), 256, 0, stream>>>(attno, woutT, out, ROWS, DIM_, DIM_);
}

// Round 2
// 563.404 us; speedup vs baseline: 1.4841x; 1.4841x over previous
//
#include <hip/hip_runtime.h>
#include <hip/hip_bf16.h>
#include <stdint.h>

#define B_    2
#define N_    2048
#define DIM_  2048
#define H_    16
#define HD_   128
#define NH3   6144            // 3*H*HD
#define ROWS  4096            // B*N
#define EPS_  1e-5f

typedef unsigned short u16;
typedef __bf16 bf16x8 __attribute__((ext_vector_type(8)));
typedef float  f32x4  __attribute__((ext_vector_type(4)));

__device__ inline f32x4 mfma16(bf16x8 a, bf16x8 b, f32x4 c) {
  return __builtin_amdgcn_mfma_f32_16x16x32_bf16(a, b, c, 0, 0, 0);
}

__device__ inline u16 f2bf(float f) {
  union { float f; uint32_t u; } v; v.f = f;
  uint32_t u = v.u;
  return (u16)((u + 0x7fffu + ((u >> 16) & 1u)) >> 16);   // RNE
}
__device__ inline float bf2f(u16 u) {
  union { uint32_t u; float f; } v; v.u = ((uint32_t)u) << 16;
  return v.f;
}

__device__ inline void gload_lds16(const void* g, void* l) {
  __builtin_amdgcn_global_load_lds(
      (const __attribute__((address_space(1))) void*)g,
      (__attribute__((address_space(3))) void*)l, 16, 0, 0);
}

// ---------------- elementwise f32 -> bf16 ----------------
__global__ __launch_bounds__(256) void cvt_f32_bf16(const float* __restrict__ in,
                                                    u16* __restrict__ out, int n) {
  int i = (blockIdx.x * 256 + threadIdx.x) * 4;
  if (i >= n) return;
  float4 v = *(const float4*)&in[i];
  ushort4 o;
  o.x = f2bf(v.x); o.y = f2bf(v.y); o.z = f2bf(v.z); o.w = f2bf(v.w);
  *(ushort4*)&out[i] = o;
}

// ---------------- tiled transpose + convert: in RxC f32 -> out CxR bf16 ----------------
__global__ __launch_bounds__(256) void transpose_cvt(const float* __restrict__ in,
                                                     u16* __restrict__ out,
                                                     int R, int C) {
  __shared__ float tile[32][33];
  int tc = blockIdx.x * 32, tr = blockIdx.y * 32;
  int tx = threadIdx.x, ty = threadIdx.y;          // 32 x 8
  #pragma unroll
  for (int i = 0; i < 4; ++i)
    tile[ty + i*8][tx] = in[(size_t)(tr + ty + i*8) * C + tc + tx];
  __syncthreads();
  #pragma unroll
  for (int i = 0; i < 4; ++i)
    out[(size_t)(tc + ty + i*8) * R + tr + tx] = f2bf(tile[tx][ty + i*8]);
}

// ---------------- V transpose: qkv V-section -> vt[bh][d][n] ----------------
// per block: one bh, 64 n-rows. LDS stride 130 u16 (65 dw, odd) -> conflict-free
__global__ __launch_bounds__(256) void v_transpose(const u16* __restrict__ qkv,
                                                   u16* __restrict__ vt) {
  __shared__ u16 lT[64][130];
  int bh = blockIdx.y, n0 = blockIdx.x * 64;
  int b = bh >> 4, h = bh & 15;
  int t = threadIdx.x;
  const u16* Vb = qkv + (size_t)b * N_ * NH3 + 4096 + h * HD_;
  #pragma unroll
  for (int i = 0; i < 16; ++i) {                 // 64 rows x 64 ushort2 chunks
    int chunk = i * 256 + t;
    int n = chunk >> 6, dc = chunk & 63;
    *(ushort2*)&lT[n][dc*2] = *(const ushort2*)&Vb[(size_t)(n0+n)*NH3 + dc*2];
  }
  __syncthreads();
  u16* vo = vt + (size_t)bh * HD_ * N_;
  #pragma unroll
  for (int i = 0; i < 4; ++i) {                  // 128 d-rows x 8 int4 chunks
    int chunk = i * 256 + t;
    int d = chunk >> 3, nc = chunk & 7;
    ushort4 a, bq;
    a.x = lT[nc*8+0][d]; a.y = lT[nc*8+1][d]; a.z = lT[nc*8+2][d]; a.w = lT[nc*8+3][d];
    bq.x = lT[nc*8+4][d]; bq.y = lT[nc*8+5][d]; bq.z = lT[nc*8+6][d]; bq.w = lT[nc*8+7][d];
    u16* dst = &vo[(size_t)d * N_ + n0 + nc*8];
    *(ushort4*)dst = a;
    *(ushort4*)(dst+4) = bq;
  }
}

// ---------------- bf16 GEMM (m97 pattern): linear LDS + global_load_lds ----------------
template <bool OUT_BF16>
__global__ __launch_bounds__(256) void gemm_bt(const u16* __restrict__ A,
                                               const u16* __restrict__ Bt,
                                               void* __restrict__ Cv,
                                               int M, int N, int K) {
  __shared__ u16 lA[128][64];   // linear (global_load_lds needs contiguous dest)
  __shared__ u16 lB[128][64];
  int m0 = blockIdx.x * 128, n0 = blockIdx.y * 128;
  int t = threadIdx.x;
  int wave = t >> 6, lane = t & 63;
  int wr = wave >> 1, wc = wave & 1;
  int lhi = lane >> 4, llo = lane & 15;
  int lrow = lane >> 3, lcol = lane & 7;         // 8 rows x 8 16B-chunks per wave-chunk
  f32x4 acc[4][4] = {};

  for (int k0 = 0; k0 < K; k0 += 64) {
    __syncthreads();
    #pragma unroll
    for (int i = 0; i < 4; ++i) {
      int chunk = i * 4 + wave;                  // 16 chunks of 8 rows each
      int row = chunk * 8 + lrow;
      gload_lds16(&A[(size_t)(m0+row)*K + k0 + lcol*8], &lA[chunk*8][0]);
      gload_lds16(&Bt[(size_t)(n0+row)*K + k0 + lcol*8], &lB[chunk*8][0]);
    }
    __syncthreads();
    #pragma unroll
    for (int kk = 0; kk < 2; ++kk) {
      bf16x8 af[4], bfr[4];
      #pragma unroll
      for (int mi = 0; mi < 4; ++mi)
        af[mi] = *(const bf16x8*)&lA[wr*64 + mi*16 + llo][kk*32 + lhi*8];
      #pragma unroll
      for (int ni = 0; ni < 4; ++ni)
        bfr[ni] = *(const bf16x8*)&lB[wc*64 + ni*16 + llo][kk*32 + lhi*8];
      #pragma unroll
      for (int mi = 0; mi < 4; ++mi)
        #pragma unroll
        for (int ni = 0; ni < 4; ++ni)
          acc[mi][ni] = mfma16(af[mi], bfr[ni], acc[mi][ni]);
    }
  }
  #pragma unroll
  for (int mi = 0; mi < 4; ++mi)
    #pragma unroll
    for (int ni = 0; ni < 4; ++ni)
      #pragma unroll
      for (int r = 0; r < 4; ++r) {
        int row = m0 + wr*64 + mi*16 + lhi*4 + r;
        int col = n0 + wc*64 + ni*16 + llo;
        float v = acc[mi][ni][r];
        if constexpr (OUT_BF16) ((u16*)Cv)[(size_t)row*N + col] = f2bf(v);
        else                    ((float*)Cv)[(size_t)row*N + col] = v;
      }
}

// ---------------- fused RMSNorm + RoPE on q,k (in-place on bf16 qkv) ----------------
__global__ __launch_bounds__(256) void norm_rope(u16* __restrict__ qkv,
                                                 const float* __restrict__ fr,
                                                 const float* __restrict__ fi,
                                                 const float* __restrict__ qw,
                                                 const float* __restrict__ kw) {
  int gw = (blockIdx.x * 256 + threadIdx.x) >> 6;
  int lane = threadIdx.x & 63;
  int row = gw >> 4, h = gw & 15;
  size_t base = (size_t)row * NH3 + h * HD_;
  ushort2 qp = *(ushort2*)&qkv[base + 2*lane];
  ushort2 kp = *(ushort2*)&qkv[base + 2048 + 2*lane];
  float q0 = bf2f(qp.x), q1 = bf2f(qp.y);
  float k0 = bf2f(kp.x), k1 = bf2f(kp.y);
  float sq = q0*q0 + q1*q1;
  float sk = k0*k0 + k1*k1;
  #pragma unroll
  for (int off = 1; off < 64; off <<= 1) {
    sq += __shfl_xor(sq, off);
    sk += __shfl_xor(sk, off);
  }
  float rq = rsqrtf(sq * (1.0f/128.0f) + EPS_);
  float rk = rsqrtf(sk * (1.0f/128.0f) + EPS_);
  float wq0 = qw[2*lane], wq1 = qw[2*lane+1];
  float wk0 = kw[2*lane], wk1 = kw[2*lane+1];
  q0 *= rq * wq0; q1 *= rq * wq1;
  k0 *= rk * wk0; k1 *= rk * wk1;
  float fre = fr[(size_t)row*64 + lane], fim = fi[(size_t)row*64 + lane];
  float qo0 = q0*fre - q1*fim, qo1 = q0*fim + q1*fre;
  float ko0 = k0*fre - k1*fim, ko1 = k0*fim + k1*fre;
  const float SC = 0.08838834764831845f;   // 1/sqrt(128) folded into q
  qo0 *= SC; qo1 *= SC;
  ushort2 qo, ko;
  qo.x = f2bf(qo0); qo.y = f2bf(qo1);
  ko.x = f2bf(ko0); ko.y = f2bf(ko1);
  *(ushort2*)&qkv[base + 2*lane] = qo;
  *(ushort2*)&qkv[base + 2048 + 2*lane] = ko;
}

// ---------------- flash attention: 128 q-rows/block (32/wave), KV tiles of 64 ----------------
__global__ __launch_bounds__(256) void attn(const u16* __restrict__ qkv,
                                            const u16* __restrict__ vt,
                                            u16* __restrict__ out) {
  int bh = blockIdx.y;
  int b = bh >> 4, h = bh & 15;
  int q0 = blockIdx.x * 128;
  int t = threadIdx.x, wave = t >> 6, lane = t & 63;
  int lhi = lane >> 4, llo = lane & 15;

  __shared__ u16 lK[64][136];      // K tile row-major (+8 pad; frag reads 2-way = free)
  __shared__ u16 lVt[128][72];     // V^T tile [d][kv] (+8 pad)
  __shared__ u16 lP[4][32][72];    // per-wave P (32x64), XOR-swizzled cols

  const u16* Qb  = qkv + (size_t)b * N_ * NH3 + h * HD_;
  const u16* Kb  = Qb + 2048;
  const u16* Vtb = vt + (size_t)bh * HD_ * N_;

  bf16x8 qf[2][4];
  #pragma unroll
  for (int pi = 0; pi < 2; ++pi) {
    const u16* qrow = Qb + (size_t)(q0 + wave*32 + pi*16 + llo) * NH3;
    #pragma unroll
    for (int kk = 0; kk < 4; ++kk)
      qf[pi][kk] = *(const bf16x8*)&qrow[kk*32 + lhi*8];
  }

  f32x4 o[2][8] = {};
  float m[2][4], l[2][4];
  #pragma unroll
  for (int pi = 0; pi < 2; ++pi)
    #pragma unroll
    for (int r = 0; r < 4; ++r) { m[pi][r] = -1e30f; l[pi][r] = 0.f; }

  for (int kv0 = 0; kv0 < N_; kv0 += 64) {
    __syncthreads();
    #pragma unroll
    for (int i = 0; i < 4; ++i) {                 // stage K (64 rows x 128 d)
      int chunk = i*256 + t;
      int row = chunk >> 4, kc = chunk & 15;
      *(int4*)&lK[row][kc*8] = *(const int4*)&Kb[(size_t)(kv0+row)*NH3 + kc*8];
    }
    #pragma unroll
    for (int i = 0; i < 4; ++i) {                 // stage V^T (128 d x 64 kv), vectorized
      int chunk = i*256 + t;
      int d = chunk >> 3, kvc = chunk & 7;
      *(int4*)&lVt[d][kvc*8] = *(const int4*)&Vtb[(size_t)d*N_ + kv0 + kvc*8];
    }
    __syncthreads();

    // S = Q K^T : rows q (32/wave), cols kv (64)
    f32x4 S[2][4];
    #pragma unroll
    for (int pi = 0; pi < 2; ++pi)
      #pragma unroll
      for (int j = 0; j < 4; ++j) S[pi][j] = f32x4{0.f,0.f,0.f,0.f};
    #pragma unroll
    for (int j = 0; j < 4; ++j)
      #pragma unroll
      for (int kk = 0; kk < 4; ++kk) {
        bf16x8 kf = *(const bf16x8*)&lK[j*16 + llo][kk*32 + lhi*8];
        S[0][j] = mfma16(qf[0][kk], kf, S[0][j]);
        S[1][j] = mfma16(qf[1][kk], kf, S[1][j]);
      }

    // online softmax (row = pi*16 + lhi*4 + r, distributed over llo)
    float sc[2][4];
    #pragma unroll
    for (int pi = 0; pi < 2; ++pi)
      #pragma unroll
      for (int r = 0; r < 4; ++r) {
        float rm = fmaxf(fmaxf(S[pi][0][r], S[pi][1][r]), fmaxf(S[pi][2][r], S[pi][3][r]));
        #pragma unroll
        for (int off = 1; off < 16; off <<= 1) rm = fmaxf(rm, __shfl_xor(rm, off));
        float mnew = fmaxf(m[pi][r], rm);
        sc[pi][r] = __expf(m[pi][r] - mnew);
        m[pi][r] = mnew;
      }
    #pragma unroll
    for (int pi = 0; pi < 2; ++pi)
      #pragma unroll
      for (int r = 0; r < 4; ++r) {
        float s0 = __expf(S[pi][0][r] - m[pi][r]);
        float s1 = __expf(S[pi][1][r] - m[pi][r]);
        float s2 = __expf(S[pi][2][r] - m[pi][r]);
        float s3 = __expf(S[pi][3][r] - m[pi][r]);
        S[pi][0][r] = s0; S[pi][1][r] = s1; S[pi][2][r] = s2; S[pi][3][r] = s3;
        float rs = s0 + s1 + s2 + s3;
        #pragma unroll
        for (int off = 1; off < 16; off <<= 1) rs += __shfl_xor(rs, off);
        l[pi][r] = l[pi][r]*sc[pi][r] + rs;
      }
    #pragma unroll
    for (int pi = 0; pi < 2; ++pi)
      #pragma unroll
      for (int d = 0; d < 8; ++d)
        #pragma unroll
        for (int r = 0; r < 4; ++r) o[pi][d][r] *= sc[pi][r];

    // P -> LDS, col XOR-swizzled by ((row>>2)&3)<<3  (write banks: 32 x 2-way = free)
    #pragma unroll
    for (int pi = 0; pi < 2; ++pi)
      #pragma unroll
      for (int j = 0; j < 4; ++j)
        #pragma unroll
        for (int r = 0; r < 4; ++r) {
          int prow = pi*16 + lhi*4 + r;
          int pcol = (j*16 + llo) ^ (lhi << 3);   // ((prow>>2)&3)<<3 == lhi<<3
          lP[wave][prow][pcol] = f2bf(S[pi][j][r]);
        }

    // PV: O += P * V   (A = P rows, B = V^T rows)
    #pragma unroll
    for (int kk = 0; kk < 2; ++kk) {
      bf16x8 pf[2];
      #pragma unroll
      for (int pi = 0; pi < 2; ++pi) {
        int prow = pi*16 + llo;
        int pcol = (kk*32 + lhi*8) ^ (((llo >> 2) & 3) << 3);
        pf[pi] = *(const bf16x8*)&lP[wave][prow][pcol];
      }
      #pragma unroll
      for (int d = 0; d < 8; ++d) {
        bf16x8 vf = *(const bf16x8*)&lVt[d*16 + llo][kk*32 + lhi*8];
        o[0][d] = mfma16(pf[0], vf, o[0][d]);
        o[1][d] = mfma16(pf[1], vf, o[1][d]);
      }
    }
  }

  #pragma unroll
  for (int pi = 0; pi < 2; ++pi)
    #pragma unroll
    for (int r = 0; r < 4; ++r) l[pi][r] = 1.0f / l[pi][r];
  #pragma unroll
  for (int pi = 0; pi < 2; ++pi)
    #pragma unroll
    for (int d = 0; d < 8; ++d)
      #pragma unroll
      for (int r = 0; r < 4; ++r) {
        size_t row = (size_t)b*N_ + q0 + wave*32 + pi*16 + lhi*4 + r;
        out[row*2048 + h*HD_ + d*16 + llo] = f2bf(o[pi][d][r] * l[pi][r]);
      }
}

extern "C" void kernel_launch(void* const* d_in, const int* in_sizes, int n_in,
                              void* d_out, int out_size, void* d_ws, size_t ws_size,
                              hipStream_t stream) {
  const float* x    = (const float*)d_in[0];
  const float* fr   = (const float*)d_in[1];
  const float* fi   = (const float*)d_in[2];
  const float* wqkv = (const float*)d_in[3];
  const float* wout = (const float*)d_in[4];
  const float* qw   = (const float*)d_in[5];
  const float* kw   = (const float*)d_in[6];
  float* out = (float*)d_out;

  char* ws = (char*)d_ws;
  const size_t SZ_XB    = (size_t)ROWS * DIM_ * 2;   // 16 MB
  const size_t SZ_WQKVT = (size_t)NH3  * DIM_ * 2;   // 24 MB
  const size_t SZ_WOUTT = (size_t)DIM_ * DIM_ * 2;   //  8 MB
  u16* xb    = (u16*)ws;
  u16* wqkvT = (u16*)(ws + SZ_XB);
  u16* woutT = (u16*)(ws + SZ_XB + SZ_WQKVT);
  u16* qkv   = (u16*)(ws + SZ_XB + SZ_WQKVT + SZ_WOUTT);
  u16* vtb   = xb;       // reuse: xb dead after GEMM1 (16 MB, exact fit)
  u16* attno = wqkvT;    // reuse: wqkvT dead after GEMM1 (needs 16 of 24 MB)

  cvt_f32_bf16<<<(ROWS*DIM_/4 + 255)/256, 256, 0, stream>>>(x, xb, ROWS*DIM_);
  transpose_cvt<<<dim3(NH3/32, DIM_/32), dim3(32, 8), 0, stream>>>(wqkv, wqkvT, DIM_, NH3);
  transpose_cvt<<<dim3(DIM_/32, DIM_/32), dim3(32, 8), 0, stream>>>(wout, woutT, DIM_, DIM_);
  gemm_bt<true ><<<dim3(ROWS/128, NH3/128), 256, 0, stream>>>(xb, wqkvT, qkv, ROWS, NH3, DIM_);
  norm_rope<<<ROWS*H_/4, 256, 0, stream>>>(qkv, fr, fi, qw, kw);
  v_transpose<<<dim3(N_/64, B_*H_), 256, 0, stream>>>(qkv, vtb);
  attn<<<dim3(N_/128, B_*H_), 256, 0, stream>>>(qkv, vtb, attno);
  gemm_bt<false><<<dim3(ROWS/128, DIM_/128), 256, 0, stream>>>(attno, woutT, out, ROWS, DIM_, DIM_);
}

// Round 9
// 551.580 us; speedup vs baseline: 1.5159x; 1.0214x over previous
//
#include <hip/hip_runtime.h>
#include <hip/hip_bf16.h>
#include <stdint.h>

#define B_    2
#define N_    2048
#define DIM_  2048
#define H_    16
#define HD_   128
#define NH3   6144            // 3*H*HD
#define ROWS  4096            // B*N
#define EPS_  1e-5f

typedef unsigned short u16;
typedef __bf16 bf16x8 __attribute__((ext_vector_type(8)));
typedef float  f32x4  __attribute__((ext_vector_type(4)));

__device__ inline f32x4 mfma16(bf16x8 a, bf16x8 b, f32x4 c) {
  return __builtin_amdgcn_mfma_f32_16x16x32_bf16(a, b, c, 0, 0, 0);
}

__device__ inline u16 f2bf(float f) {
  union { float f; uint32_t u; } v; v.f = f;
  uint32_t u = v.u;
  return (u16)((u + 0x7fffu + ((u >> 16) & 1u)) >> 16);   // RNE
}
__device__ inline float bf2f(u16 u) {
  union { uint32_t u; float f; } v; v.u = ((uint32_t)u) << 16;
  return v.f;
}

__device__ inline void gload_lds16(const void* g, void* l) {
  __builtin_amdgcn_global_load_lds(
      (const __attribute__((address_space(1))) void*)g,
      (__attribute__((address_space(3))) void*)l, 16, 0, 0);
}

// ---------------- elementwise f32 -> bf16 ----------------
__global__ __launch_bounds__(256) void cvt_f32_bf16(const float* __restrict__ in,
                                                    u16* __restrict__ out, int n) {
  int i = (blockIdx.x * 256 + threadIdx.x) * 4;
  if (i >= n) return;
  float4 v = *(const float4*)&in[i];
  ushort4 o;
  o.x = f2bf(v.x); o.y = f2bf(v.y); o.z = f2bf(v.z); o.w = f2bf(v.w);
  *(ushort4*)&out[i] = o;
}

// ---------------- tiled transpose + convert: in RxC f32 -> out CxR bf16 ----------------
__global__ __launch_bounds__(256) void transpose_cvt(const float* __restrict__ in,
                                                     u16* __restrict__ out,
                                                     int R, int C) {
  __shared__ float tile[32][33];
  int tc = blockIdx.x * 32, tr = blockIdx.y * 32;
  int tx = threadIdx.x, ty = threadIdx.y;          // 32 x 8
  #pragma unroll
  for (int i = 0; i < 4; ++i)
    tile[ty + i*8][tx] = in[(size_t)(tr + ty + i*8) * C + tc + tx];
  __syncthreads();
  #pragma unroll
  for (int i = 0; i < 4; ++i)
    out[(size_t)(tc + ty + i*8) * R + tr + tx] = f2bf(tile[tx][ty + i*8]);
}

// ---------------- V transpose: qkv V-section -> vt[bh][d][n] ----------------
__global__ __launch_bounds__(256) void v_transpose(const u16* __restrict__ qkv,
                                                   u16* __restrict__ vt) {
  __shared__ u16 lT[64][130];
  int bh = blockIdx.y, n0 = blockIdx.x * 64;
  int b = bh >> 4, h = bh & 15;
  int t = threadIdx.x;
  const u16* Vb = qkv + (size_t)b * N_ * NH3 + 4096 + h * HD_;
  #pragma unroll
  for (int i = 0; i < 16; ++i) {
    int chunk = i * 256 + t;
    int n = chunk >> 6, dc = chunk & 63;
    *(ushort2*)&lT[n][dc*2] = *(const ushort2*)&Vb[(size_t)(n0+n)*NH3 + dc*2];
  }
  __syncthreads();
  u16* vo = vt + (size_t)bh * HD_ * N_;
  #pragma unroll
  for (int i = 0; i < 4; ++i) {
    int chunk = i * 256 + t;
    int d = chunk >> 3, nc = chunk & 7;
    ushort4 a, bq;
    a.x = lT[nc*8+0][d]; a.y = lT[nc*8+1][d]; a.z = lT[nc*8+2][d]; a.w = lT[nc*8+3][d];
    bq.x = lT[nc*8+4][d]; bq.y = lT[nc*8+5][d]; bq.z = lT[nc*8+6][d]; bq.w = lT[nc*8+7][d];
    u16* dst = &vo[(size_t)d * N_ + n0 + nc*8];
    *(ushort4*)dst = a;
    *(ushort4*)(dst+4) = bq;
  }
}

// ---------------- bf16 GEMM (m97 pattern + XCD swizzle), 1D grid ----------------
template <bool OUT_BF16>
__global__ __launch_bounds__(256) void gemm_bt(const u16* __restrict__ A,
                                               const u16* __restrict__ Bt,
                                               void* __restrict__ Cv,
                                               int M, int N, int K) {
  __shared__ u16 lA[128][64];
  __shared__ u16 lB[128][64];
  // XCD-aware swizzle: consecutive nid on one XCD share the Bt panel (L2-resident)
  int per = gridDim.x >> 3;
  int nid = (blockIdx.x & 7) * per + (blockIdx.x >> 3);
  int MB = M >> 7;
  int m0 = (nid % MB) * 128, n0 = (nid / MB) * 128;
  int t = threadIdx.x;
  int wave = t >> 6, lane = t & 63;
  int wr = wave >> 1, wc = wave & 1;
  int lhi = lane >> 4, llo = lane & 15;
  int lrow = lane >> 3, lcol = lane & 7;
  f32x4 acc[4][4] = {};

  for (int k0 = 0; k0 < K; k0 += 64) {
    __syncthreads();
    #pragma unroll
    for (int i = 0; i < 4; ++i) {
      int chunk = i * 4 + wave;
      int row = chunk * 8 + lrow;
      gload_lds16(&A[(size_t)(m0+row)*K + k0 + lcol*8], &lA[chunk*8][0]);
      gload_lds16(&Bt[(size_t)(n0+row)*K + k0 + lcol*8], &lB[chunk*8][0]);
    }
    __syncthreads();
    #pragma unroll
    for (int kk = 0; kk < 2; ++kk) {
      bf16x8 af[4], bfr[4];
      #pragma unroll
      for (int mi = 0; mi < 4; ++mi)
        af[mi] = *(const bf16x8*)&lA[wr*64 + mi*16 + llo][kk*32 + lhi*8];
      #pragma unroll
      for (int ni = 0; ni < 4; ++ni)
        bfr[ni] = *(const bf16x8*)&lB[wc*64 + ni*16 + llo][kk*32 + lhi*8];
      #pragma unroll
      for (int mi = 0; mi < 4; ++mi)
        #pragma unroll
        for (int ni = 0; ni < 4; ++ni)
          acc[mi][ni] = mfma16(af[mi], bfr[ni], acc[mi][ni]);
    }
  }
  #pragma unroll
  for (int mi = 0; mi < 4; ++mi)
    #pragma unroll
    for (int ni = 0; ni < 4; ++ni)
      #pragma unroll
      for (int r = 0; r < 4; ++r) {
        int row = m0 + wr*64 + mi*16 + lhi*4 + r;
        int col = n0 + wc*64 + ni*16 + llo;
        float v = acc[mi][ni][r];
        if constexpr (OUT_BF16) ((u16*)Cv)[(size_t)row*N + col] = f2bf(v);
        else                    ((float*)Cv)[(size_t)row*N + col] = v;
      }
}

// ---------------- fused RMSNorm + RoPE on q,k ----------------
__global__ __launch_bounds__(256) void norm_rope(u16* __restrict__ qkv,
                                                 const float* __restrict__ fr,
                                                 const float* __restrict__ fi,
                                                 const float* __restrict__ qw,
                                                 const float* __restrict__ kw) {
  int gw = (blockIdx.x * 256 + threadIdx.x) >> 6;
  int lane = threadIdx.x & 63;
  int row = gw >> 4, h = gw & 15;
  size_t base = (size_t)row * NH3 + h * HD_;
  ushort2 qp = *(ushort2*)&qkv[base + 2*lane];
  ushort2 kp = *(ushort2*)&qkv[base + 2048 + 2*lane];
  float q0 = bf2f(qp.x), q1 = bf2f(qp.y);
  float k0 = bf2f(kp.x), k1 = bf2f(kp.y);
  float sq = q0*q0 + q1*q1;
  float sk = k0*k0 + k1*k1;
  #pragma unroll
  for (int off = 1; off < 64; off <<= 1) {
    sq += __shfl_xor(sq, off);
    sk += __shfl_xor(sk, off);
  }
  float rq = rsqrtf(sq * (1.0f/128.0f) + EPS_);
  float rk = rsqrtf(sk * (1.0f/128.0f) + EPS_);
  float wq0 = qw[2*lane], wq1 = qw[2*lane+1];
  float wk0 = kw[2*lane], wk1 = kw[2*lane+1];
  q0 *= rq * wq0; q1 *= rq * wq1;
  k0 *= rk * wk0; k1 *= rk * wk1;
  float fre = fr[(size_t)row*64 + lane], fim = fi[(size_t)row*64 + lane];
  float qo0 = q0*fre - q1*fim, qo1 = q0*fim + q1*fre;
  float ko0 = k0*fre - k1*fim, ko1 = k0*fim + k1*fre;
  const float SC = 0.08838834764831845f;   // 1/sqrt(128) folded into q
  qo0 *= SC; qo1 *= SC;
  ushort2 qo, ko;
  qo.x = f2bf(qo0); qo.y = f2bf(qo1);
  ko.x = f2bf(ko0); ko.y = f2bf(ko1);
  *(ushort2*)&qkv[base + 2*lane] = qo;
  *(ushort2*)&qkv[base + 2048 + 2*lane] = ko;
}

// ---------------- flash attention, swapped-QK^T softmax ----------------
// 128 q-rows/block (32/wave), KV tiles of 64. St = mfma(K,Q): lane holds 16 kv
// values of q-row (lane&15) -> in-lane softmax, 2 shuffles per stat, packed P writes.
__global__ __launch_bounds__(256) void attn(const u16* __restrict__ qkv,
                                            const u16* __restrict__ vt,
                                            u16* __restrict__ out) {
  // XCD swizzle: the 16 q-tiles of one bh stay on one XCD (K/V L2-resident)
  int nid = (blockIdx.x & 7) * 64 + (blockIdx.x >> 3);
  int bh = nid >> 4;
  int b = bh >> 4, h = bh & 15;
  int q0 = (nid & 15) * 128;
  int t = threadIdx.x, wave = t >> 6, lane = t & 63;
  int lhi = lane >> 4, llo = lane & 15;

  __shared__ u16 lK[64][136];
  __shared__ u16 lVt[128][72];
  __shared__ u16 lP[4][32][72];    // per-wave P: [q 0..31][kv 0..63]

  const u16* Qb  = qkv + (size_t)b * N_ * NH3 + h * HD_;
  const u16* Kb  = Qb + 2048;
  const u16* Vtb = vt + (size_t)bh * HD_ * N_;

  bf16x8 qf[2][4];
  #pragma unroll
  for (int pi = 0; pi < 2; ++pi) {
    const u16* qrow = Qb + (size_t)(q0 + wave*32 + pi*16 + llo) * NH3;
    #pragma unroll
    for (int kk = 0; kk < 4; ++kk)
      qf[pi][kk] = *(const bf16x8*)&qrow[kk*32 + lhi*8];
  }

  f32x4 o[2][8] = {};
  float m_own[2] = {-1e30f, -1e30f};    // running max for q = pi*16+llo (x4 replicated)
  float l_own[2] = {0.f, 0.f};

  for (int kv0 = 0; kv0 < N_; kv0 += 64) {
    __syncthreads();
    #pragma unroll
    for (int i = 0; i < 4; ++i) {                 // stage K (64 rows x 128 d)
      int chunk = i*256 + t;
      int row = chunk >> 4, kc = chunk & 15;
      *(int4*)&lK[row][kc*8] = *(const int4*)&Kb[(size_t)(kv0+row)*NH3 + kc*8];
    }
    #pragma unroll
    for (int i = 0; i < 4; ++i) {                 // stage V^T (128 d x 64 kv)
      int chunk = i*256 + t;
      int d = chunk >> 3, kvc = chunk & 7;
      *(int4*)&lVt[d][kvc*8] = *(const int4*)&Vtb[(size_t)d*N_ + kv0 + kvc*8];
    }
    __syncthreads();

    // St[pi][j][r] = S[kv = j*16+lhi*4+r][q = pi*16+llo]   (swapped operands)
    f32x4 St[2][4];
    #pragma unroll
    for (int pi = 0; pi < 2; ++pi)
      #pragma unroll
      for (int j = 0; j < 4; ++j) St[pi][j] = f32x4{0.f,0.f,0.f,0.f};
    #pragma unroll
    for (int j = 0; j < 4; ++j)
      #pragma unroll
      for (int kk = 0; kk < 4; ++kk) {
        bf16x8 kf = *(const bf16x8*)&lK[j*16 + llo][kk*32 + lhi*8];
        St[0][j] = mfma16(kf, qf[0][kk], St[0][j]);
        St[1][j] = mfma16(kf, qf[1][kk], St[1][j]);
      }

    // per-lane online softmax for own q-row, then broadcast rescale factors
    float scb[2][4];
    #pragma unroll
    for (int pi = 0; pi < 2; ++pi) {
      float mx = -1e30f;
      #pragma unroll
      for (int j = 0; j < 4; ++j) {
        float a = fmaxf(fmaxf(St[pi][j][0], St[pi][j][1]),
                        fmaxf(St[pi][j][2], St[pi][j][3]));
        mx = fmaxf(mx, a);
      }
      mx = fmaxf(mx, __shfl_xor(mx, 16));
      mx = fmaxf(mx, __shfl_xor(mx, 32));
      float mnew = fmaxf(m_own[pi], mx);
      float sc = __expf(m_own[pi] - mnew);
      m_own[pi] = mnew;
      float rs = 0.f;
      #pragma unroll
      for (int j = 0; j < 4; ++j)
        #pragma unroll
        for (int r = 0; r < 4; ++r) {
          float p = __expf(St[pi][j][r] - mnew);
          St[pi][j][r] = p;
          rs += p;
        }
      rs += __shfl_xor(rs, 16);
      rs += __shfl_xor(rs, 32);
      l_own[pi] = l_own[pi] * sc + rs;
      // lane needs sc of q-row (pi*16 + lhi*4 + r) for its o rows
      #pragma unroll
      for (int r = 0; r < 4; ++r) scb[pi][r] = __shfl(sc, lhi*4 + r, 16);
    }
    #pragma unroll
    for (int pi = 0; pi < 2; ++pi)
      #pragma unroll
      for (int d = 0; d < 8; ++d)
        #pragma unroll
        for (int r = 0; r < 4; ++r) o[pi][d][r] *= scb[pi][r];

    // P write: lane owns q=pi*16+llo, kv=j*16+lhi*4..+3 -> contiguous ds_write_b64
    #pragma unroll
    for (int pi = 0; pi < 2; ++pi)
      #pragma unroll
      for (int j = 0; j < 4; ++j) {
        union { ushort4 u; __bf16 hv[4]; } pw;
        #pragma unroll
        for (int r = 0; r < 4; ++r) pw.hv[r] = (__bf16)St[pi][j][r];
        *(ushort4*)&lP[wave][pi*16 + llo][j*16 + lhi*4] = pw.u;
      }

    // PV: O += P * V  (A = P rows q, B = V^T rows d); same-wave DS ordering
    #pragma unroll
    for (int kk = 0; kk < 2; ++kk) {
      bf16x8 pf[2];
      #pragma unroll
      for (int pi = 0; pi < 2; ++pi)
        pf[pi] = *(const bf16x8*)&lP[wave][pi*16 + llo][kk*32 + lhi*8];
      #pragma unroll
      for (int d = 0; d < 8; ++d) {
        bf16x8 vf = *(const bf16x8*)&lVt[d*16 + llo][kk*32 + lhi*8];
        o[0][d] = mfma16(pf[0], vf, o[0][d]);
        o[1][d] = mfma16(pf[1], vf, o[1][d]);
      }
    }
  }

  float linv[2][4];
  #pragma unroll
  for (int pi = 0; pi < 2; ++pi)
    #pragma unroll
    for (int r = 0; r < 4; ++r)
      linv[pi][r] = 1.0f / __shfl(l_own[pi], lhi*4 + r, 16);
  #pragma unroll
  for (int pi = 0; pi < 2; ++pi)
    #pragma unroll
    for (int d = 0; d < 8; ++d)
      #pragma unroll
      for (int r = 0; r < 4; ++r) {
        size_t row = (size_t)b*N_ + q0 + wave*32 + pi*16 + lhi*4 + r;
        out[row*2048 + h*HD_ + d*16 + llo] = f2bf(o[pi][d][r] * linv[pi][r]);
      }
}

extern "C" void kernel_launch(void* const* d_in, const int* in_sizes, int n_in,
                              void* d_out, int out_size, void* d_ws, size_t ws_size,
                              hipStream_t stream) {
  const float* x    = (const float*)d_in[0];
  const float* fr   = (const float*)d_in[1];
  const float* fi   = (const float*)d_in[2];
  const float* wqkv = (const float*)d_in[3];
  const float* wout = (const float*)d_in[4];
  const float* qw   = (const float*)d_in[5];
  const float* kw   = (const float*)d_in[6];
  float* out = (float*)d_out;

  char* ws = (char*)d_ws;
  const size_t SZ_XB    = (size_t)ROWS * DIM_ * 2;   // 16 MB
  const size_t SZ_WQKVT = (size_t)NH3  * DIM_ * 2;   // 24 MB
  const size_t SZ_WOUTT = (size_t)DIM_ * DIM_ * 2;   //  8 MB
  u16* xb    = (u16*)ws;
  u16* wqkvT = (u16*)(ws + SZ_XB);
  u16* woutT = (u16*)(ws + SZ_XB + SZ_WQKVT);
  u16* qkv   = (u16*)(ws + SZ_XB + SZ_WQKVT + SZ_WOUTT);
  u16* vtb   = xb;       // reuse: xb dead after GEMM1
  u16* attno = wqkvT;    // reuse: wqkvT dead after GEMM1

  cvt_f32_bf16<<<(ROWS*DIM_/4 + 255)/256, 256, 0, stream>>>(x, xb, ROWS*DIM_);
  transpose_cvt<<<dim3(NH3/32, DIM_/32), dim3(32, 8), 0, stream>>>(wqkv, wqkvT, DIM_, NH3);
  transpose_cvt<<<dim3(DIM_/32, DIM_/32), dim3(32, 8), 0, stream>>>(wout, woutT, DIM_, DIM_);
  gemm_bt<true ><<<(ROWS/128)*(NH3/128), 256, 0, stream>>>(xb, wqkvT, qkv, ROWS, NH3, DIM_);
  norm_rope<<<ROWS*H_/4, 256, 0, stream>>>(qkv, fr, fi, qw, kw);
  v_transpose<<<dim3(N_/64, B_*H_), 256, 0, stream>>>(qkv, vtb);
  attn<<<(N_/128)*(B_*H_), 256, 0, stream>>>(qkv, vtb, attno);
  gemm_bt<false><<<(ROWS/128)*(DIM_/128), 256, 0, stream>>>(attno, woutT, out, ROWS, DIM_, DIM_);
}